// Round 5
// baseline (250.298 us; speedup 1.0000x reference)
//
#include <hip/hip_runtime.h>
#include <math.h>

#define NT 256      // threads per block
#define NS 4096     // 2^12 amplitudes

typedef float f32x2 __attribute__((ext_vector_type(2)));

// CNOT ring: gates CNOT(i,(i+1)%12), wire j <-> bit (11-j).
// forward basis permutation pi(k), GF(2)-linear:
constexpr int ring_pi_c(int k) {
    int u = k ^ (k >> 1);
    u ^= u >> 2; u ^= u >> 4; u ^= u >> 8;
    int w0 = ((u >> 11) ^ u) & 1;
    return (u & 0x7FF) | (w0 << 11);
}
// storage swizzle (GF(2)-linear): rank-4 bank map for P0/P1/P2 reads+writes
constexpr int sig2(int m) { return m ^ ((m >> 4) & 0xF) ^ ((m >> 8) & 0xF); }

// Fused gate G = [[A-iB, -C+iD],[C+iD, A+iB]] applied to (a0,a1), packed fp32.
__device__ __forceinline__ void app1p(f32x2 ab, f32x2 cd, f32x2& a0, f32x2& a1) {
    f32x2 n0, n1;
    asm("v_pk_mul_f32 %0, %2, %4 op_sel:[0,0] op_sel_hi:[1,0]\n\t"
        "v_pk_fma_f32 %0, %2, %4, %0 op_sel:[1,1,0] op_sel_hi:[0,1,1] neg_hi:[0,1,0]\n\t"
        "v_pk_fma_f32 %0, %3, %5, %0 op_sel:[0,0,0] op_sel_hi:[1,0,1] neg_lo:[0,1,0] neg_hi:[0,1,0]\n\t"
        "v_pk_fma_f32 %0, %3, %5, %0 op_sel:[1,1,0] op_sel_hi:[0,1,1] neg_lo:[0,1,0]\n\t"
        "v_pk_mul_f32 %1, %3, %4 op_sel:[0,0] op_sel_hi:[1,0]\n\t"
        "v_pk_fma_f32 %1, %3, %4, %1 op_sel:[1,1,0] op_sel_hi:[0,1,1] neg_lo:[0,1,0]\n\t"
        "v_pk_fma_f32 %1, %2, %5, %1 op_sel:[0,0,0] op_sel_hi:[1,0,1]\n\t"
        "v_pk_fma_f32 %1, %2, %5, %1 op_sel:[1,1,0] op_sel_hi:[0,1,1] neg_lo:[0,1,0]"
        : "=&v"(n0), "=&v"(n1)
        : "v"(a0), "v"(a1), "v"(ab), "v"(cd));
    a0 = n0; a1 = n1;
}

template<int P>
__device__ __forceinline__ void gate_on_bit(f32x2 a[16], f32x2 ab, f32x2 cd) {
    #pragma unroll
    for (int r = 0; r < 16; ++r)
        if (!(r & (1 << P)))
            app1p(ab, cd, a[r], a[r | (1 << P)]);
}

// load fused gate; for l==3 fold in RX(x[b*24+12+w]) (ABCD closed form)
__device__ __forceinline__ void load_gate(const float4* __restrict__ Uw,
                                          const float2* __restrict__ cs12,
                                          int l, int w, bool fold,
                                          f32x2& ab, f32x2& cd) {
    float4 g = Uw[l * 12 + w];
    float A = g.x, B = g.y, C = g.z, D = g.w;
    if (fold) {
        float2 sc = cs12[w];
        float c = sc.x, s = sc.y;
        float A2 = A*c + D*s, B2 = B*c - C*s, C2 = C*c + B*s, D2 = D*c - A*s;
        A = A2; B = B2; C = C2; D = D2;
    }
    ab = f32x2{A, B}; cd = f32x2{C, D};
}

// ---- prep kernel: cos/sin of all encode half-angles + batch-independent fused U
__global__ void prep_kernel(const float* __restrict__ x,     // (B,24)
                            const float* __restrict__ wts,   // (6,3,12)
                            float4* __restrict__ Uw,         // 72
                            float2* __restrict__ cs,         // B*24
                            int total)                       // B*24
{
    int idx = blockIdx.x * blockDim.x + threadIdx.x;
    if (idx < total) {
        float th = 0.5f * x[idx];
        float s, c; sincosf(th, &s, &c);
        cs[idx] = make_float2(c, s);
    }
    if (idx < 72) {
        int ab = idx / 12, w = idx % 12;
        float a  = 0.5f * wts[(ab * 3 + 0) * 12 + w];
        float bb = 0.5f * wts[(ab * 3 + 1) * 12 + w];
        float g  = 0.5f * wts[(ab * 3 + 2) * 12 + w];
        float sa, ca, sb, cb, sg, cg;
        sincosf(a,  &sa, &ca);
        sincosf(bb, &sb, &cb);
        sincosf(g,  &sg, &cg);
        float A = cb * (ca * cg - sa * sg);
        float B = sb * (ca * cg + sa * sg);
        float C = cb * (sa * cg + ca * sg);
        float D = sb * (sa * cg - ca * sg);
        Uw[idx] = make_float4(A, B, C, D);
    }
}

__global__ __launch_bounds__(NT, 5)   // 5 waves/EU -> VGPR cap 102; LDS 32KB -> 5 blocks/CU
void tqhea_kernel(const float4* __restrict__ Uw,   // 72 fused gates (ABCD)
                  const float2* __restrict__ cs,   // (B,24) encode (cos,sin)
                  float* __restrict__ out)         // (B,1)
{
    __shared__ f32x2 psi[NS];        // 32 KB exactly, sig2-swizzled storage

    const int b = blockIdx.x;
    const int t = threadIdx.x;

    const int lo = t & 0xF, h = t >> 4;
    const int tb     = (t & 0xF0) | (lo ^ h);          // P0/init: addr = (r<<8)|(tb^r)
    const int baseP1 = (h << 8) | (lo ^ h);            // P1: addr = baseP1 ^ 17r
    const int baseP2 = (t << 4) | (lo ^ h);            // P2: addr = baseP2 ^ r
    const int Qt     = sig2(ring_pi_c(t << 4));        // ring scatter: addr = Qt ^ sig2(pi(r))
    const int Pt     = ring_pi_c(t << 4);              // reduction diag

    const float2* csb  = cs + b * 24;                  // block-uniform
    const float2* cs12 = csb + 12;

    // ---- init: |0..0> + first RX layer = product state (write-only pass)
    {
        float2 rc[12];
        #pragma unroll
        for (int i = 0; i < 12; ++i) rc[i] = csb[i];   // uniform scalar loads
        float mlo = 1.f;
        #pragma unroll
        for (int bit = 0; bit < 8; ++bit)              // k bit 'bit' <-> wire 11-bit
            mlo *= ((t >> bit) & 1) ? rc[11 - bit].y : rc[11 - bit].x;
        int pct = __popc(t);
        #pragma unroll
        for (int r = 0; r < 16; ++r) {
            float mhi = 1.f;
            #pragma unroll
            for (int p = 0; p < 4; ++p)                // r bit p <-> wire 3-p
                mhi *= ((r >> p) & 1) ? rc[3 - p].y : rc[3 - p].x;
            float mag = mhi * mlo;
            int pc = (pct + __popc(r)) & 3;            // (-i)^popcount phase
            f32x2 v;
            v.x = (pc == 0) ? mag : ((pc == 2) ? -mag : 0.f);
            v.y = (pc == 1) ? -mag : ((pc == 3) ? mag : 0.f);
            psi[(r << 8) | (tb ^ r)] = v;
        }
    }
    __syncthreads();

    float acc = 0.f;

    // ---- 6 ansatz layers; ring folded into P2 scatter-write (layers 0..4),
    //      last layer's ring + P2 fold straight into the reduction
    #pragma unroll 1
    for (int l = 0; l < 6; ++l) {
        const bool fold = (l == 3);                    // mid-circuit RX layer folded in
        f32x2 a[16];
        f32x2 gab, gcd;

        // P0: wires 0..3 (k bits 11..8 register-local)
        #pragma unroll
        for (int r = 0; r < 16; ++r) a[r] = psi[(r << 8) | (tb ^ r)];
        load_gate(Uw, cs12, l, 0, fold, gab, gcd); gate_on_bit<3>(a, gab, gcd);
        load_gate(Uw, cs12, l, 1, fold, gab, gcd); gate_on_bit<2>(a, gab, gcd);
        load_gate(Uw, cs12, l, 2, fold, gab, gcd); gate_on_bit<1>(a, gab, gcd);
        load_gate(Uw, cs12, l, 3, fold, gab, gcd); gate_on_bit<0>(a, gab, gcd);
        #pragma unroll
        for (int r = 0; r < 16; ++r) psi[(r << 8) | (tb ^ r)] = a[r];
        __syncthreads();

        // P1: wires 4..7 (k bits 7..4 register-local)
        #pragma unroll
        for (int r = 0; r < 16; ++r) a[r] = psi[baseP1 ^ (17 * r)];
        load_gate(Uw, cs12, l, 4, fold, gab, gcd); gate_on_bit<3>(a, gab, gcd);
        load_gate(Uw, cs12, l, 5, fold, gab, gcd); gate_on_bit<2>(a, gab, gcd);
        load_gate(Uw, cs12, l, 6, fold, gab, gcd); gate_on_bit<1>(a, gab, gcd);
        load_gate(Uw, cs12, l, 7, fold, gab, gcd); gate_on_bit<0>(a, gab, gcd);
        #pragma unroll
        for (int r = 0; r < 16; ++r) psi[baseP1 ^ (17 * r)] = a[r];
        __syncthreads();

        // P2: wires 8..11 (k bits 3..0 register-local); thread t, reg r hold k=(t<<4)|r
        #pragma unroll
        for (int r = 0; r < 16; ++r) a[r] = psi[baseP2 ^ r];
        if (l < 5) __syncthreads();        // all P2 reads complete before ring scatter
        load_gate(Uw, cs12, l, 8,  fold, gab, gcd); gate_on_bit<3>(a, gab, gcd);
        load_gate(Uw, cs12, l, 9,  fold, gab, gcd); gate_on_bit<2>(a, gab, gcd);
        load_gate(Uw, cs12, l, 10, fold, gab, gcd); gate_on_bit<1>(a, gab, gcd);
        load_gate(Uw, cs12, l, 11, fold, gab, gcd); gate_on_bit<0>(a, gab, gcd);
        if (l < 5) {
            // ring fold: psi_new[sig2(pi(k))] = a[r];  pi linear -> addr = Qt ^ const
            #pragma unroll
            for (int r = 0; r < 16; ++r)
                psi[Qt ^ sig2(ring_pi_c(r))] = a[r];
            __syncthreads();
        } else {
            // ---- <H>: final ring via pi; diag = 12 - 2*popc(pi(k))
            #pragma unroll
            for (int r = 0; r < 16; ++r) {
                float d = 12.0f - 2.0f * (float)__popc(Pt ^ ring_pi_c(r));
                acc += (a[r].x * a[r].x + a[r].y * a[r].y) * d;
            }
        }
    }

    // ---- reduce: wave shfl, then cross-wave via psi reuse
    #pragma unroll
    for (int off = 32; off > 0; off >>= 1)
        acc += __shfl_down(acc, off);
    __syncthreads();                       // all psi reads done; safe to reuse
    if ((t & 63) == 0) ((float*)psi)[t >> 6] = acc;
    __syncthreads();
    if (t == 0) {
        const float* rb = (const float*)psi;
        out[b] = rb[0] + rb[1] + rb[2] + rb[3];
    }
}

extern "C" void kernel_launch(void* const* d_in, const int* in_sizes, int n_in,
                              void* d_out, int out_size, void* d_ws, size_t ws_size,
                              hipStream_t stream) {
    const float* x   = (const float*)d_in[0];   // (B, 24) float32
    const float* wts = (const float*)d_in[1];   // (6, 3, 12) float32
    float* out = (float*)d_out;                 // (B, 1) float32
    int B = in_sizes[0] / 24;

    float4* Uw = (float4*)d_ws;                       // 72 * 16 B
    float2* cs = (float2*)((char*)d_ws + 1152);       // B*24 * 8 B
    int total = B * 24;

    prep_kernel<<<dim3((total + NT - 1) / NT), dim3(NT), 0, stream>>>(x, wts, Uw, cs, total);
    tqhea_kernel<<<dim3(B), dim3(NT), 0, stream>>>(Uw, cs, out);
}

// Round 6
// 217.025 us; speedup vs baseline: 1.1533x; 1.1533x over previous
//
#include <hip/hip_runtime.h>
#include <math.h>

#define NT 256      // threads per block
#define NS 4096     // 2^12 amplitudes

typedef float f32x2 __attribute__((ext_vector_type(2)));

// CNOT ring: gates CNOT(i,(i+1)%12), wire j <-> bit (11-j).
// forward basis permutation pi(k), GF(2)-linear:
constexpr int ring_pi_c(int k) {
    int u = k ^ (k >> 1);
    u ^= u >> 2; u ^= u >> 4; u ^= u >> 8;
    int w0 = ((u >> 11) ^ u) & 1;
    return (u & 0x7FF) | (w0 << 11);
}
// storage swizzle (GF(2)-linear): rank-4 bank map for P0/P1/P2 reads+writes
constexpr int sig2(int m) { return m ^ ((m >> 4) & 0xF) ^ ((m >> 8) & 0xF); }

// Fused gate G = [[A-iB, -C+iD],[C+iD, A+iB]] applied to (a0,a1), packed fp32.
__device__ __forceinline__ void app1p(f32x2 ab, f32x2 cd, f32x2& a0, f32x2& a1) {
    f32x2 n0, n1;
    asm("v_pk_mul_f32 %0, %2, %4 op_sel:[0,0] op_sel_hi:[1,0]\n\t"
        "v_pk_fma_f32 %0, %2, %4, %0 op_sel:[1,1,0] op_sel_hi:[0,1,1] neg_hi:[0,1,0]\n\t"
        "v_pk_fma_f32 %0, %3, %5, %0 op_sel:[0,0,0] op_sel_hi:[1,0,1] neg_lo:[0,1,0] neg_hi:[0,1,0]\n\t"
        "v_pk_fma_f32 %0, %3, %5, %0 op_sel:[1,1,0] op_sel_hi:[0,1,1] neg_lo:[0,1,0]\n\t"
        "v_pk_mul_f32 %1, %3, %4 op_sel:[0,0] op_sel_hi:[1,0]\n\t"
        "v_pk_fma_f32 %1, %3, %4, %1 op_sel:[1,1,0] op_sel_hi:[0,1,1] neg_lo:[0,1,0]\n\t"
        "v_pk_fma_f32 %1, %2, %5, %1 op_sel:[0,0,0] op_sel_hi:[1,0,1]\n\t"
        "v_pk_fma_f32 %1, %2, %5, %1 op_sel:[1,1,0] op_sel_hi:[0,1,1] neg_lo:[0,1,0]"
        : "=&v"(n0), "=&v"(n1)
        : "v"(a0), "v"(a1), "v"(ab), "v"(cd));
    a0 = n0; a1 = n1;
}

template<int P>
__device__ __forceinline__ void gate_on_bit(f32x2 a[16], f32x2 ab, f32x2 cd) {
    #pragma unroll
    for (int r = 0; r < 16; ++r)
        if (!(r & (1 << P)))
            app1p(ab, cd, a[r], a[r | (1 << P)]);
}

// load fused gate; for l==3 fold in RX(x[b*24+12+w]) (ABCD closed form)
__device__ __forceinline__ void load_gate(const float4* __restrict__ Uw,
                                          const float2* __restrict__ cs12,
                                          int l, int w, bool fold,
                                          f32x2& ab, f32x2& cd) {
    float4 g = Uw[l * 12 + w];
    float A = g.x, B = g.y, C = g.z, D = g.w;
    if (fold) {
        float2 sc = cs12[w];
        float c = sc.x, s = sc.y;
        float A2 = A*c + D*s, B2 = B*c - C*s, C2 = C*c + B*s, D2 = D*c - A*s;
        A = A2; B = B2; C = C2; D = D2;
    }
    ab = f32x2{A, B}; cd = f32x2{C, D};
}

// ---- prep kernel: cos/sin of all encode half-angles + batch-independent fused U
__global__ void prep_kernel(const float* __restrict__ x,     // (B,24)
                            const float* __restrict__ wts,   // (6,3,12)
                            float4* __restrict__ Uw,         // 72
                            float2* __restrict__ cs,         // B*24
                            int total)                       // B*24
{
    int idx = blockIdx.x * blockDim.x + threadIdx.x;
    if (idx < total) {
        float th = 0.5f * x[idx];
        float s, c; sincosf(th, &s, &c);
        cs[idx] = make_float2(c, s);
    }
    if (idx < 72) {
        int ab = idx / 12, w = idx % 12;
        float a  = 0.5f * wts[(ab * 3 + 0) * 12 + w];
        float bb = 0.5f * wts[(ab * 3 + 1) * 12 + w];
        float g  = 0.5f * wts[(ab * 3 + 2) * 12 + w];
        float sa, ca, sb, cb, sg, cg;
        sincosf(a,  &sa, &ca);
        sincosf(bb, &sb, &cb);
        sincosf(g,  &sg, &cg);
        float A = cb * (ca * cg - sa * sg);
        float B = sb * (ca * cg + sa * sg);
        float C = cb * (sa * cg + ca * sg);
        float D = sb * (sa * cg - ca * sg);
        Uw[idx] = make_float4(A, B, C, D);
    }
}

__global__ __launch_bounds__(NT, 4)   // VGPR cap 128 (no spill, proven at 72); LDS 32KB -> 5 blocks/CU
void tqhea_kernel(const float4* __restrict__ Uw,   // 72 fused gates (ABCD)
                  const float2* __restrict__ cs,   // (B,24) encode (cos,sin)
                  float* __restrict__ out)         // (B,1)
{
    __shared__ f32x2 psi[NS];        // 32 KB exactly, sig2-swizzled storage

    const int b = blockIdx.x;
    const int t = threadIdx.x;

    const int lo = t & 0xF, h = t >> 4;
    const int tb     = (t & 0xF0) | (lo ^ h);          // P0/init: addr = (r<<8)|(tb^r)
    const int baseP1 = (h << 8) | (lo ^ h);            // P1: addr = baseP1 ^ 17r
    const int baseP2 = (t << 4) | (lo ^ h);            // P2: addr = baseP2 ^ r
    const int Qt     = sig2(ring_pi_c(t << 4));        // ring scatter: addr = Qt ^ sig2(pi(r))
    const int Pt     = ring_pi_c(t << 4);              // reduction diag

    const float2* csb  = cs + b * 24;                  // block-uniform
    const float2* cs12 = csb + 12;

    // ---- init: |0..0> + first RX layer = product state (write-only pass)
    {
        float2 rc[12];
        #pragma unroll
        for (int i = 0; i < 12; ++i) rc[i] = csb[i];   // uniform scalar loads
        float mlo = 1.f;
        #pragma unroll
        for (int bit = 0; bit < 8; ++bit)              // k bit 'bit' <-> wire 11-bit
            mlo *= ((t >> bit) & 1) ? rc[11 - bit].y : rc[11 - bit].x;
        int pct = __popc(t);
        #pragma unroll
        for (int r = 0; r < 16; ++r) {
            float mhi = 1.f;
            #pragma unroll
            for (int p = 0; p < 4; ++p)                // r bit p <-> wire 3-p
                mhi *= ((r >> p) & 1) ? rc[3 - p].y : rc[3 - p].x;
            float mag = mhi * mlo;
            int pc = (pct + __popc(r)) & 3;            // (-i)^popcount phase
            f32x2 v;
            v.x = (pc == 0) ? mag : ((pc == 2) ? -mag : 0.f);
            v.y = (pc == 1) ? -mag : ((pc == 3) ? mag : 0.f);
            psi[(r << 8) | (tb ^ r)] = v;
        }
    }
    __syncthreads();

    float acc = 0.f;

    // ---- 6 ansatz layers; ring folded into P2 scatter-write (layers 0..4),
    //      last layer's ring + P2 fold straight into the reduction
    #pragma unroll 1
    for (int l = 0; l < 6; ++l) {
        const bool fold = (l == 3);                    // mid-circuit RX layer folded in
        f32x2 a[16];
        f32x2 gab, gcd;

        // P0: wires 0..3 (k bits 11..8 register-local)
        #pragma unroll
        for (int r = 0; r < 16; ++r) a[r] = psi[(r << 8) | (tb ^ r)];
        load_gate(Uw, cs12, l, 0, fold, gab, gcd); gate_on_bit<3>(a, gab, gcd);
        load_gate(Uw, cs12, l, 1, fold, gab, gcd); gate_on_bit<2>(a, gab, gcd);
        load_gate(Uw, cs12, l, 2, fold, gab, gcd); gate_on_bit<1>(a, gab, gcd);
        load_gate(Uw, cs12, l, 3, fold, gab, gcd); gate_on_bit<0>(a, gab, gcd);
        #pragma unroll
        for (int r = 0; r < 16; ++r) psi[(r << 8) | (tb ^ r)] = a[r];
        __syncthreads();

        // P1: wires 4..7 (k bits 7..4 register-local)
        #pragma unroll
        for (int r = 0; r < 16; ++r) a[r] = psi[baseP1 ^ (17 * r)];
        load_gate(Uw, cs12, l, 4, fold, gab, gcd); gate_on_bit<3>(a, gab, gcd);
        load_gate(Uw, cs12, l, 5, fold, gab, gcd); gate_on_bit<2>(a, gab, gcd);
        load_gate(Uw, cs12, l, 6, fold, gab, gcd); gate_on_bit<1>(a, gab, gcd);
        load_gate(Uw, cs12, l, 7, fold, gab, gcd); gate_on_bit<0>(a, gab, gcd);
        #pragma unroll
        for (int r = 0; r < 16; ++r) psi[baseP1 ^ (17 * r)] = a[r];
        __syncthreads();

        // P2: wires 8..11 (k bits 3..0 register-local); thread t, reg r hold k=(t<<4)|r
        #pragma unroll
        for (int r = 0; r < 16; ++r) a[r] = psi[baseP2 ^ r];
        if (l < 5) __syncthreads();        // all P2 reads complete before ring scatter
        load_gate(Uw, cs12, l, 8,  fold, gab, gcd); gate_on_bit<3>(a, gab, gcd);
        load_gate(Uw, cs12, l, 9,  fold, gab, gcd); gate_on_bit<2>(a, gab, gcd);
        load_gate(Uw, cs12, l, 10, fold, gab, gcd); gate_on_bit<1>(a, gab, gcd);
        load_gate(Uw, cs12, l, 11, fold, gab, gcd); gate_on_bit<0>(a, gab, gcd);
        if (l < 5) {
            // ring fold: psi_new[sig2(pi(k))] = a[r];  pi linear -> addr = Qt ^ const
            #pragma unroll
            for (int r = 0; r < 16; ++r)
                psi[Qt ^ sig2(ring_pi_c(r))] = a[r];
            __syncthreads();
        } else {
            // ---- <H>: final ring via pi; diag = 12 - 2*popc(pi(k))
            #pragma unroll
            for (int r = 0; r < 16; ++r) {
                float d = 12.0f - 2.0f * (float)__popc(Pt ^ ring_pi_c(r));
                acc += (a[r].x * a[r].x + a[r].y * a[r].y) * d;
            }
        }
    }

    // ---- reduce: wave shfl, then cross-wave via psi reuse
    #pragma unroll
    for (int off = 32; off > 0; off >>= 1)
        acc += __shfl_down(acc, off);
    __syncthreads();                       // all psi reads done; safe to reuse
    if ((t & 63) == 0) ((float*)psi)[t >> 6] = acc;
    __syncthreads();
    if (t == 0) {
        const float* rb = (const float*)psi;
        out[b] = rb[0] + rb[1] + rb[2] + rb[3];
    }
}

extern "C" void kernel_launch(void* const* d_in, const int* in_sizes, int n_in,
                              void* d_out, int out_size, void* d_ws, size_t ws_size,
                              hipStream_t stream) {
    const float* x   = (const float*)d_in[0];   // (B, 24) float32
    const float* wts = (const float*)d_in[1];   // (6, 3, 12) float32
    float* out = (float*)d_out;                 // (B, 1) float32
    int B = in_sizes[0] / 24;

    float4* Uw = (float4*)d_ws;                       // 72 * 16 B
    float2* cs = (float2*)((char*)d_ws + 1152);       // B*24 * 8 B
    int total = B * 24;

    prep_kernel<<<dim3((total + NT - 1) / NT), dim3(NT), 0, stream>>>(x, wts, Uw, cs, total);
    tqhea_kernel<<<dim3(B), dim3(NT), 0, stream>>>(Uw, cs, out);
}

// Round 7
// 215.359 us; speedup vs baseline: 1.1622x; 1.0077x over previous
//
#include <hip/hip_runtime.h>
#include <math.h>

#define NT 256      // threads per block
#define NS 4096     // 2^12 amplitudes

typedef float f32x2 __attribute__((ext_vector_type(2)));

// CNOT ring: gates CNOT(i,(i+1)%12), wire j <-> bit (11-j).
// forward basis permutation pi(k), GF(2)-linear:
constexpr int ring_pi_c(int k) {
    int u = k ^ (k >> 1);
    u ^= u >> 2; u ^= u >> 4; u ^= u >> 8;
    int w0 = ((u >> 11) ^ u) & 1;
    return (u & 0x7FF) | (w0 << 11);
}
// storage swizzle (GF(2)-linear): rank-4 bank map for P0/P1/P2 reads+writes
constexpr int sig2(int m) { return m ^ ((m >> 4) & 0xF) ^ ((m >> 8) & 0xF); }

// Fused gate G = [[A-iB, -C+iD],[C+iD, A+iB]] applied to (a0,a1), packed fp32.
__device__ __forceinline__ void app1p(f32x2 ab, f32x2 cd, f32x2& a0, f32x2& a1) {
    f32x2 n0, n1;
    asm("v_pk_mul_f32 %0, %2, %4 op_sel:[0,0] op_sel_hi:[1,0]\n\t"
        "v_pk_fma_f32 %0, %2, %4, %0 op_sel:[1,1,0] op_sel_hi:[0,1,1] neg_hi:[0,1,0]\n\t"
        "v_pk_fma_f32 %0, %3, %5, %0 op_sel:[0,0,0] op_sel_hi:[1,0,1] neg_lo:[0,1,0] neg_hi:[0,1,0]\n\t"
        "v_pk_fma_f32 %0, %3, %5, %0 op_sel:[1,1,0] op_sel_hi:[0,1,1] neg_lo:[0,1,0]\n\t"
        "v_pk_mul_f32 %1, %3, %4 op_sel:[0,0] op_sel_hi:[1,0]\n\t"
        "v_pk_fma_f32 %1, %3, %4, %1 op_sel:[1,1,0] op_sel_hi:[0,1,1] neg_lo:[0,1,0]\n\t"
        "v_pk_fma_f32 %1, %2, %5, %1 op_sel:[0,0,0] op_sel_hi:[1,0,1]\n\t"
        "v_pk_fma_f32 %1, %2, %5, %1 op_sel:[1,1,0] op_sel_hi:[0,1,1] neg_lo:[0,1,0]"
        : "=&v"(n0), "=&v"(n1)
        : "v"(a0), "v"(a1), "v"(ab), "v"(cd));
    a0 = n0; a1 = n1;
}

template<int P>
__device__ __forceinline__ void gate_on_bit(f32x2 a[16], f32x2 ab, f32x2 cd) {
    #pragma unroll
    for (int r = 0; r < 16; ++r)
        if (!(r & (1 << P)))
            app1p(ab, cd, a[r], a[r | (1 << P)]);
}

// load fused gate; for l==3 fold in RX(x[b*24+12+w]) (ABCD closed form)
__device__ __forceinline__ void load_gate(const float4* __restrict__ Uw,
                                          const float2* __restrict__ cs12,
                                          int l, int w, bool fold,
                                          f32x2& ab, f32x2& cd) {
    float4 g = Uw[l * 12 + w];
    float A = g.x, B = g.y, C = g.z, D = g.w;
    if (fold) {
        float2 sc = cs12[w];
        float c = sc.x, s = sc.y;
        float A2 = A*c + D*s, B2 = B*c - C*s, C2 = C*c + B*s, D2 = D*c - A*s;
        A = A2; B = B2; C = C2; D = D2;
    }
    ab = f32x2{A, B}; cd = f32x2{C, D};
}

// ---- prep kernel: cos/sin of all encode half-angles + batch-independent fused U
__global__ void prep_kernel(const float* __restrict__ x,     // (B,24)
                            const float* __restrict__ wts,   // (6,3,12)
                            float4* __restrict__ Uw,         // 72
                            float2* __restrict__ cs,         // B*24
                            int total)                       // B*24
{
    int idx = blockIdx.x * blockDim.x + threadIdx.x;
    if (idx < total) {
        float th = 0.5f * x[idx];
        float s, c; sincosf(th, &s, &c);
        cs[idx] = make_float2(c, s);
    }
    if (idx < 72) {
        int ab = idx / 12, w = idx % 12;
        float a  = 0.5f * wts[(ab * 3 + 0) * 12 + w];
        float bb = 0.5f * wts[(ab * 3 + 1) * 12 + w];
        float g  = 0.5f * wts[(ab * 3 + 2) * 12 + w];
        float sa, ca, sb, cb, sg, cg;
        sincosf(a,  &sa, &ca);
        sincosf(bb, &sb, &cb);
        sincosf(g,  &sg, &cg);
        float A = cb * (ca * cg - sa * sg);
        float B = sb * (ca * cg + sa * sg);
        float C = cb * (sa * cg + ca * sg);
        float D = sb * (sa * cg - ca * sg);
        Uw[idx] = make_float4(A, B, C, D);
    }
}

__global__ __launch_bounds__(NT, 2)   // (256,2): only proven no-spill config (R4); LDS 32KB -> 5 blocks/CU
void tqhea_kernel(const float4* __restrict__ Uw,   // 72 fused gates (ABCD)
                  const float2* __restrict__ cs,   // (B,24) encode (cos,sin)
                  float* __restrict__ out)         // (B,1)
{
    __shared__ f32x2 psi[NS];        // 32 KB exactly, sig2-swizzled storage

    const int b = blockIdx.x;
    const int t = threadIdx.x;

    const int lo = t & 0xF, h = t >> 4;
    const int tb     = (t & 0xF0) | (lo ^ h);          // P0/init: addr = (r<<8)|(tb^r)
    const int baseP1 = (h << 8) | (lo ^ h);            // P1: addr = baseP1 ^ 17r
    const int baseP2 = (t << 4) | (lo ^ h);            // P2: addr = baseP2 ^ r
    const int Qt     = sig2(ring_pi_c(t << 4));        // ring scatter: addr = Qt ^ sig2(pi(r))
    const int Pt     = ring_pi_c(t << 4);              // reduction diag

    const float2* csb  = cs + b * 24;                  // block-uniform
    const float2* cs12 = csb + 12;

    // ---- init: |0..0> + first RX layer = product state (write-only pass)
    {
        float2 rc[12];
        #pragma unroll
        for (int i = 0; i < 12; ++i) rc[i] = csb[i];   // uniform scalar loads
        float mlo = 1.f;
        #pragma unroll
        for (int bit = 0; bit < 8; ++bit)              // k bit 'bit' <-> wire 11-bit
            mlo *= ((t >> bit) & 1) ? rc[11 - bit].y : rc[11 - bit].x;
        int pct = __popc(t);
        #pragma unroll
        for (int r = 0; r < 16; ++r) {
            float mhi = 1.f;
            #pragma unroll
            for (int p = 0; p < 4; ++p)                // r bit p <-> wire 3-p
                mhi *= ((r >> p) & 1) ? rc[3 - p].y : rc[3 - p].x;
            float mag = mhi * mlo;
            int pc = (pct + __popc(r)) & 3;            // (-i)^popcount phase
            f32x2 v;
            v.x = (pc == 0) ? mag : ((pc == 2) ? -mag : 0.f);
            v.y = (pc == 1) ? -mag : ((pc == 3) ? mag : 0.f);
            psi[(r << 8) | (tb ^ r)] = v;
        }
    }
    __syncthreads();

    float acc = 0.f;

    // ---- 6 ansatz layers; ring folded into P2 scatter-write (layers 0..4),
    //      last layer's ring + P2 fold straight into the reduction
    #pragma unroll 1
    for (int l = 0; l < 6; ++l) {
        const bool fold = (l == 3);                    // mid-circuit RX layer folded in
        f32x2 a[16];
        f32x2 gab, gcd;

        // P0: wires 0..3 (k bits 11..8 register-local)
        #pragma unroll
        for (int r = 0; r < 16; ++r) a[r] = psi[(r << 8) | (tb ^ r)];
        load_gate(Uw, cs12, l, 0, fold, gab, gcd); gate_on_bit<3>(a, gab, gcd);
        load_gate(Uw, cs12, l, 1, fold, gab, gcd); gate_on_bit<2>(a, gab, gcd);
        load_gate(Uw, cs12, l, 2, fold, gab, gcd); gate_on_bit<1>(a, gab, gcd);
        load_gate(Uw, cs12, l, 3, fold, gab, gcd); gate_on_bit<0>(a, gab, gcd);
        #pragma unroll
        for (int r = 0; r < 16; ++r) psi[(r << 8) | (tb ^ r)] = a[r];
        __syncthreads();

        // P1: wires 4..7 (k bits 7..4 register-local)
        #pragma unroll
        for (int r = 0; r < 16; ++r) a[r] = psi[baseP1 ^ (17 * r)];
        load_gate(Uw, cs12, l, 4, fold, gab, gcd); gate_on_bit<3>(a, gab, gcd);
        load_gate(Uw, cs12, l, 5, fold, gab, gcd); gate_on_bit<2>(a, gab, gcd);
        load_gate(Uw, cs12, l, 6, fold, gab, gcd); gate_on_bit<1>(a, gab, gcd);
        load_gate(Uw, cs12, l, 7, fold, gab, gcd); gate_on_bit<0>(a, gab, gcd);
        #pragma unroll
        for (int r = 0; r < 16; ++r) psi[baseP1 ^ (17 * r)] = a[r];
        __syncthreads();

        // P2: wires 8..11 (k bits 3..0 register-local); thread t, reg r hold k=(t<<4)|r
        #pragma unroll
        for (int r = 0; r < 16; ++r) a[r] = psi[baseP2 ^ r];
        if (l < 5) __syncthreads();        // all P2 reads complete before ring scatter
        load_gate(Uw, cs12, l, 8,  fold, gab, gcd); gate_on_bit<3>(a, gab, gcd);
        load_gate(Uw, cs12, l, 9,  fold, gab, gcd); gate_on_bit<2>(a, gab, gcd);
        load_gate(Uw, cs12, l, 10, fold, gab, gcd); gate_on_bit<1>(a, gab, gcd);
        load_gate(Uw, cs12, l, 11, fold, gab, gcd); gate_on_bit<0>(a, gab, gcd);
        if (l < 5) {
            // ring fold: psi_new[sig2(pi(k))] = a[r];  pi linear -> addr = Qt ^ const
            #pragma unroll
            for (int r = 0; r < 16; ++r)
                psi[Qt ^ sig2(ring_pi_c(r))] = a[r];
            __syncthreads();
        } else {
            // ---- <H>: final ring via pi; diag = 12 - 2*popc(pi(k))
            #pragma unroll
            for (int r = 0; r < 16; ++r) {
                float d = 12.0f - 2.0f * (float)__popc(Pt ^ ring_pi_c(r));
                acc += (a[r].x * a[r].x + a[r].y * a[r].y) * d;
            }
        }
    }

    // ---- reduce: wave shfl, then cross-wave via psi reuse
    #pragma unroll
    for (int off = 32; off > 0; off >>= 1)
        acc += __shfl_down(acc, off);
    __syncthreads();                       // all psi reads done; safe to reuse
    if ((t & 63) == 0) ((float*)psi)[t >> 6] = acc;
    __syncthreads();
    if (t == 0) {
        const float* rb = (const float*)psi;
        out[b] = rb[0] + rb[1] + rb[2] + rb[3];
    }
}

extern "C" void kernel_launch(void* const* d_in, const int* in_sizes, int n_in,
                              void* d_out, int out_size, void* d_ws, size_t ws_size,
                              hipStream_t stream) {
    const float* x   = (const float*)d_in[0];   // (B, 24) float32
    const float* wts = (const float*)d_in[1];   // (6, 3, 12) float32
    float* out = (float*)d_out;                 // (B, 1) float32
    int B = in_sizes[0] / 24;

    float4* Uw = (float4*)d_ws;                       // 72 * 16 B
    float2* cs = (float2*)((char*)d_ws + 1152);       // B*24 * 8 B
    int total = B * 24;

    prep_kernel<<<dim3((total + NT - 1) / NT), dim3(NT), 0, stream>>>(x, wts, Uw, cs, total);
    tqhea_kernel<<<dim3(B), dim3(NT), 0, stream>>>(Uw, cs, out);
}